// Round 8
// baseline (25183.861 us; speedup 1.0000x reference)
//
#include <hip/hip_runtime.h>
#include <hip/hip_fp16.h>

typedef _Float16 h2_t __attribute__((ext_vector_type(2)));
typedef unsigned int u32x4 __attribute__((ext_vector_type(4)));

#define KEXP 2.8853900817779268f  // 2/ln2

// raw barrier: drain LDS only; global loads stay in flight
#define BARRIER() do { \
    asm volatile("s_waitcnt lgkmcnt(0)" ::: "memory"); \
    __builtin_amdgcn_s_barrier(); \
    asm volatile("" ::: "memory"); \
} while (0)

__device__ __forceinline__ float fdot2(unsigned int a, unsigned int b, float c) {
#if __has_builtin(__builtin_amdgcn_fdot2)
    return __builtin_amdgcn_fdot2(__builtin_bit_cast(h2_t, a), __builtin_bit_cast(h2_t, b), c, false);
#else
    h2_t ha = __builtin_bit_cast(h2_t, a), hb = __builtin_bit_cast(h2_t, b);
    return c + (float)ha[0]*(float)hb[0] + (float)ha[1]*(float)hb[1];
#endif
}

__device__ __forceinline__ float dot4(u32x4 a, u32x4 b, float c) {
    c = fdot2(a[0], b[0], c); c = fdot2(a[1], b[1], c);
    c = fdot2(a[2], b[2], c); c = fdot2(a[3], b[3], c);
    return c;
}

__device__ __forceinline__ unsigned int pk16(float a, float b) {
    auto h = __builtin_amdgcn_cvt_pkrtz(a, b);
    return __builtin_bit_cast(unsigned int, h);
}

__device__ __forceinline__ float rcp_(float x) {
#if __has_builtin(__builtin_amdgcn_rcpf)
    return __builtin_amdgcn_rcpf(x);
#else
    return 1.0f / x;
#endif
}

__device__ __forceinline__ float sigm(float x) { return rcp_(1.0f + __expf(-x)); }
__device__ __forceinline__ float tanh_(float x) {
    float e = __expf(2.0f * x);
    return 1.0f - 2.0f * rcp_(e + 1.0f);
}

__device__ __forceinline__ unsigned int rcp1p2exp(unsigned int s) {
    __half2 e = h2exp2(__builtin_bit_cast(__half2, s));
    __half2 d = __hadd2(e, __float2half2_rn(1.0f));
    return __builtin_bit_cast(unsigned int, h2rcp(d));
}
__device__ __forceinline__ unsigned int hadd2u(unsigned int a, unsigned int b) {
    return __builtin_bit_cast(unsigned int,
        __hadd2(__builtin_bit_cast(__half2, a), __builtin_bit_cast(__half2, b)));
}

__device__ __forceinline__ void st_u32(unsigned int* p, unsigned int v) {
    __hip_atomic_store(p, v, __ATOMIC_RELAXED, __HIP_MEMORY_SCOPE_AGENT);
}
__device__ __forceinline__ unsigned int ld_u32(const unsigned int* p) {
    return __hip_atomic_load(p, __ATOMIC_RELAXED, __HIP_MEMORY_SCOPE_AGENT);
}
__device__ __forceinline__ float ld_f32(const unsigned int* p) {
    return __builtin_bit_cast(float, ld_u32(p));
}
__device__ __forceinline__ float h2f_lo(unsigned int v) {
    return __half2float(__ushort_as_half((unsigned short)(v & 0xffffu)));
}
__device__ __forceinline__ float h2f_hi(unsigned int v) {
    return __half2float(__ushort_as_half((unsigned short)(v >> 16)));
}

__global__ void init_flags_kernel(unsigned int* flags) {
    flags[threadIdx.x * 32] = 0u;
}

// ---- prep: pack weights to f16, layout [k8][j]: u32x4 = 8 halves of row j, cols 8k8..8k8+7 ----
__global__ __launch_bounds__(256) void prep_kernel(
    const float* __restrict__ encWhh, const float* __restrict__ decWih,
    const float* __restrict__ decWhh, const float* __restrict__ W2w,
    u32x4* __restrict__ We8, u32x4* __restrict__ Wi8, u32x4* __restrict__ Wh8, u32x4* __restrict__ W28)
{
    int id = blockIdx.x * 256 + threadIdx.x;
    if (id < 3 * 32768) {
        int mat = id >> 15, local = id & 32767;
        int j = local & 1023, k8 = local >> 10;
        const float* src = mat == 0 ? encWhh : (mat == 1 ? decWih : decWhh);
        u32x4* dst = mat == 0 ? We8 : (mat == 1 ? Wi8 : Wh8);
        const float* p = src + (size_t)j * 256 + k8 * 8;
        float4 a = *(const float4*)p; float4 c = *(const float4*)(p + 4);
        u32x4 v; v[0] = pk16(a.x, a.y); v[1] = pk16(a.z, a.w);
        v[2] = pk16(c.x, c.y); v[3] = pk16(c.z, c.w);
        dst[k8 * 1024 + j] = v;
    } else {
        int local = id - 3 * 32768;
        if (local < 8192) {
            int m = local & 255, k8 = local >> 8;
            const float* p = W2w + (size_t)m * 256 + k8 * 8;
            float4 a = *(const float4*)p; float4 c = *(const float4*)(p + 4);
            u32x4 v; v[0] = pk16(a.x, a.y); v[1] = pk16(a.z, a.w);
            v[2] = pk16(c.x, c.y); v[3] = pk16(c.z, c.w);
            W28[k8 * 256 + m] = v;
        }
    }
}

// ---- GEMM: C(f16) = (A[M][256] * Bw[N][256]^T + bias) * scale
// TR_OUT=0: C[M][N] row-major.  TR_OUT=1 (proj): C = projT[b][c8(32)][s(512)] 16B granules.
template<int A_IS_F16, int TR_OUT>
__global__ __launch_bounds__(256) void gemm_kernel(
    const void* __restrict__ A_, const float* __restrict__ Bw,
    const float* __restrict__ bias, unsigned short* __restrict__ C, int N, float scale)
{
    __shared__ float As[16][68];
    __shared__ float Bs[16][132];
    const int t = threadIdx.x;
    const int row0 = blockIdx.y * 64, col0 = blockIdx.x * 128;
    const int ty = t >> 4, tx = t & 15;
    const int lm = t & 63, lkq = t >> 6;
    const int ln = t & 127, lkq2 = t >> 7;
    float acc[4][8] = {};
    for (int k0 = 0; k0 < 256; k0 += 16) {
        float4 av;
        if constexpr (A_IS_F16) {
            const unsigned short* A = (const unsigned short*)A_;
            uint2 ha = *(const uint2*)(A + (size_t)(row0 + lm) * 256 + k0 + lkq * 4);
            h2_t h0 = __builtin_bit_cast(h2_t, ha.x);
            h2_t h1 = __builtin_bit_cast(h2_t, ha.y);
            av = make_float4((float)h0[0], (float)h0[1], (float)h1[0], (float)h1[1]);
        } else {
            av = *(const float4*)((const float*)A_ + (size_t)(row0 + lm) * 256 + k0 + lkq * 4);
        }
        const float* bp = Bw + (size_t)(col0 + ln) * 256 + k0 + lkq2 * 8;
        float4 bv0 = *(const float4*)bp;
        float4 bv1 = *(const float4*)(bp + 4);
        __syncthreads();
        As[lkq * 4 + 0][lm] = av.x;
        As[lkq * 4 + 1][lm] = av.y;
        As[lkq * 4 + 2][lm] = av.z;
        As[lkq * 4 + 3][lm] = av.w;
        Bs[lkq2 * 8 + 0][ln] = bv0.x;
        Bs[lkq2 * 8 + 1][ln] = bv0.y;
        Bs[lkq2 * 8 + 2][ln] = bv0.z;
        Bs[lkq2 * 8 + 3][ln] = bv0.w;
        Bs[lkq2 * 8 + 4][ln] = bv1.x;
        Bs[lkq2 * 8 + 5][ln] = bv1.y;
        Bs[lkq2 * 8 + 6][ln] = bv1.z;
        Bs[lkq2 * 8 + 7][ln] = bv1.w;
        __syncthreads();
        #pragma unroll
        for (int kk = 0; kk < 16; ++kk) {
            float4 a = *(float4*)&As[kk][ty * 4];
            float4 b0 = *(float4*)&Bs[kk][tx * 8];
            float4 b1 = *(float4*)&Bs[kk][tx * 8 + 4];
            float ar[4] = {a.x, a.y, a.z, a.w};
            float br[8] = {b0.x, b0.y, b0.z, b0.w, b1.x, b1.y, b1.z, b1.w};
            #pragma unroll
            for (int i = 0; i < 4; ++i)
                #pragma unroll
                for (int j = 0; j < 8; ++j)
                    acc[i][j] = fmaf(ar[i], br[j], acc[i][j]);
        }
    }
    float bv[8];
    #pragma unroll
    for (int j = 0; j < 8; ++j) bv[j] = bias[col0 + tx * 8 + j];
    #pragma unroll
    for (int i = 0; i < 4; ++i) {
        unsigned int w0 = pk16((acc[i][0] + bv[0]) * scale, (acc[i][1] + bv[1]) * scale);
        unsigned int w1 = pk16((acc[i][2] + bv[2]) * scale, (acc[i][3] + bv[3]) * scale);
        unsigned int w2 = pk16((acc[i][4] + bv[4]) * scale, (acc[i][5] + bv[5]) * scale);
        unsigned int w3 = pk16((acc[i][6] + bv[6]) * scale, (acc[i][7] + bv[7]) * scale);
        uint4 val = make_uint4(w0, w1, w2, w3);
        if constexpr (TR_OUT) {
            int rr = row0 + ty * 4 + i;
            int bb = rr >> 9, s = rr & 511;
            int c8 = (col0 >> 3) + tx;
            ((uint4*)C)[(size_t)bb * 16384 + (size_t)c8 * 512 + s] = val;
        } else {
            *(uint4*)(C + (size_t)(row0 + ty * 4 + i) * N + col0 + tx * 8) = val;
        }
    }
}

// ---- encoder: 1 block per batch; emits enc_h [b][s][h] f16 and encT [b][c(64)][h(256)] 16B granules ----
__global__ __launch_bounds__(1024) void encoder_kernel(
    const unsigned short* __restrict__ Xproj, const u32x4* __restrict__ We8,
    float* __restrict__ hfin, float* __restrict__ cfin,
    unsigned short* __restrict__ enc_h, unsigned int* __restrict__ encT)
{
    const int b = blockIdx.x, t = threadIdx.x;
    __shared__ __align__(16) float zs[1024];
    __shared__ __align__(16) unsigned int hh2[128];
    if (t < 128) hh2[t] = 0u;
    float c_reg = 0.f, hprev = 0.f, hcur = 0.f;
    __syncthreads();
    const unsigned short* xp = Xproj + (size_t)b * 512 * 1024 + t;
    for (int step = 0; step < 512; ++step) {
        float acc = __half2float(__ushort_as_half(__builtin_nontemporal_load(xp)));
        #pragma unroll 8
        for (int k8 = 0; k8 < 32; ++k8) {
            u32x4 wv = We8[k8 * 1024 + t];
            u32x4 hv = *(const u32x4*)&hh2[k8 * 4];
            acc = dot4(wv, hv, acc);
        }
        zs[t] = acc;
        __syncthreads();
        if (t < 256) {
            float ig = sigm(zs[t]), fg = sigm(zs[t + 256]);
            float gg = tanh_(zs[t + 512]), og = sigm(zs[t + 768]);
            c_reg = fg * c_reg + ig * gg;
            float h = og * tanh_(c_reg);
            float hnb = __shfl_down(h, 1);
            if (!(t & 1)) hh2[t >> 1] = pk16(h, hnb);
            __builtin_nontemporal_store(__half_as_ushort(__float2half_rn(h)),
                                        enc_h + (size_t)(b * 512 + step) * 256 + t);
            if (step & 1) {
                int s2 = step >> 1;
                encT[(size_t)b * 65536 + (size_t)((s2 >> 2) * 256 + t) * 4 + (s2 & 3)] = pk16(hprev, h);
            }
            hprev = h; hcur = h;
        }
        __syncthreads();
        xp += 1024;
    }
    if (t < 256) { hfin[b * 256 + t] = hcur; cfin[b * 256 + t] = c_reg; }
}

// ---- decoder: 32 groups x 4 blocks (block g owns gate g + s-quarter), 4 batches per group,
//      Wih/Whh register-resident, 2 rendezvous/step; 128 blocks total (2x co-residency slack) ----
__global__ __launch_bounds__(512, 2) void decoder_kernel(
    const u32x4* __restrict__ Wi8, const u32x4* __restrict__ Wh8, const u32x4* __restrict__ W28,
    const float* __restrict__ dec_b, const float* __restrict__ W2b, const float* __restrict__ vtw,
    const float* __restrict__ hfin, const float* __restrict__ cfin,
    const u32x4* __restrict__ projT, const u32x4* __restrict__ encT,
    unsigned int* __restrict__ xgate, unsigned int* __restrict__ xdin,
    unsigned int* __restrict__ xsum, unsigned int* __restrict__ flags,
    float* __restrict__ out)
{
    const int blk = blockIdx.x;
    const int gr = blk & 31, g = blk >> 5;   // group gr = blocks {gr, gr+32, gr+64, gr+96} (same XCD residue)
    const int t = threadIdx.x;
    const int lane = t & 63, w = t >> 6;
    const int bbase = gr * 4;

    __shared__ float zsp[4][512];
    __shared__ __align__(16) unsigned int hh2[4][128];
    __shared__ __align__(16) unsigned int din2[4][128];
    __shared__ __align__(16) unsigned int qp2[4][128];
    __shared__ __align__(16) unsigned int mv2u[128];
    __shared__ __align__(16) unsigned int p2u[4][64];
    __shared__ float wreds[8][4];
    __shared__ float svtS, rsS[4];

    // ---- register-resident weights: thread (r = t&255, kh = t>>8) of gate g ----
    const int r = t & 255, kh = t >> 8;
    u32x4 wih[16], whh[16];
    #pragma unroll
    for (int i = 0; i < 16; ++i) wih[i] = Wi8[(size_t)(kh * 16 + i) * 1024 + g * 256 + r];
    #pragma unroll
    for (int i = 0; i < 16; ++i) whh[i] = Wh8[(size_t)(kh * 16 + i) * 1024 + g * 256 + r];

    float cA[4], cB[4];
    #pragma unroll
    for (int b = 0; b < 4; ++b) { cA[b] = 0.f; cB[b] = 0.f; }
    if (t < 128) {
        #pragma unroll
        for (int b = 0; b < 4; ++b) {
            cA[b] = cfin[(bbase + b) * 256 + 2 * t];
            cB[b] = cfin[(bbase + b) * 256 + 2 * t + 1];
            din2[b][t] = 0u;
        }
        mv2u[t] = pk16(-2.f * vtw[2 * t], -2.f * vtw[2 * t + 1]);
    }
    const float bja = (t < 256) ? dec_b[g * 256 + t] : 0.f;
    const float w2b_r = (t < 256) ? W2b[t] : 0.f;
    if (t < 256) zsp[0][t] = vtw[t];
    __syncthreads();
    if (t < 64) {
        float v = zsp[0][t] + zsp[0][t + 64] + zsp[0][t + 128] + zsp[0][t + 192];
        #pragma unroll
        for (int off = 1; off < 64; off <<= 1) v += __shfl_xor(v, off);
        if (t == 0) svtS = v;
    }
    if (t < 256) {
        #pragma unroll
        for (int b = 0; b < 4; ++b) {
            float h0 = hfin[(bbase + b) * 256 + t];
            float h0n = __shfl_down(h0, 1);
            if (!(t & 1)) hh2[b][t >> 1] = pk16(h0, h0n);
        }
    }
    __syncthreads();
    const float svt = svtS;

    const int q4 = gr * 4 + g;
    unsigned int* fl_me = flags + q4 * 32;
    unsigned int* fl_p0 = flags + (gr * 4 + ((g + 1) & 3)) * 32;
    unsigned int* fl_p1 = flags + (gr * 4 + ((g + 2) & 3)) * 32;
    unsigned int* fl_p2 = flags + (gr * 4 + ((g + 3) & 3)) * 32;
    unsigned int* xg_me = xgate + q4 * 512;
    unsigned int* xd_me = xdin + q4 * 1024;

    // phase D mapping: 4 threads per s; block's s-range = [g*128, g*128+128)
    const int sl = t >> 2, qr = t & 3;
    // phase F mapping: h = t&255, chunk-half t>>8 within block's 16 encT chunks
    const int hF = t & 255, scF = t >> 8;
    const size_t pDoff = (size_t)(qr * 8) * 512 + g * 128 + sl;
    const size_t fDoff = (size_t)(g * 16 + scF * 8) * 256 + hF;

    for (int step = 0; step < 512; ++step) {
        // ---- A: z partials for my gate's 256 rows, 4 batches (register weights) ----
        {
            float a0 = 0.f, a1 = 0.f, a2 = 0.f, a3 = 0.f;
            #pragma unroll
            for (int i = 0; i < 16; ++i) {
                u32x4 wv = wih[i];
                u32x4 d0 = *(const u32x4*)&din2[0][kh * 64 + i * 4];
                u32x4 d1 = *(const u32x4*)&din2[1][kh * 64 + i * 4];
                u32x4 d2 = *(const u32x4*)&din2[2][kh * 64 + i * 4];
                u32x4 d3 = *(const u32x4*)&din2[3][kh * 64 + i * 4];
                a0 = dot4(wv, d0, a0); a1 = dot4(wv, d1, a1);
                a2 = dot4(wv, d2, a2); a3 = dot4(wv, d3, a3);
            }
            #pragma unroll
            for (int i = 0; i < 16; ++i) {
                u32x4 wv = whh[i];
                u32x4 h0 = *(const u32x4*)&hh2[0][kh * 64 + i * 4];
                u32x4 h1 = *(const u32x4*)&hh2[1][kh * 64 + i * 4];
                u32x4 h2 = *(const u32x4*)&hh2[2][kh * 64 + i * 4];
                u32x4 h3 = *(const u32x4*)&hh2[3][kh * 64 + i * 4];
                a0 = dot4(wv, h0, a0); a1 = dot4(wv, h1, a1);
                a2 = dot4(wv, h2, a2); a3 = dot4(wv, h3, a3);
            }
            zsp[0][t] = a0; zsp[1][t] = a1; zsp[2][t] = a2; zsp[3][t] = a3;
        }
        BARRIER();
        // ---- B: my gate for 4 batches -> exchange ----
        if (t < 256) {
            float gv[4];
            #pragma unroll
            for (int b = 0; b < 4; ++b) {
                float z = bja + zsp[b][t] + zsp[b][t + 256];
                gv[b] = (g == 2) ? tanh_(z) : sigm(z);
            }
            st_u32(&xg_me[t], pk16(gv[0], gv[1]));
            st_u32(&xg_me[256 + t], pk16(gv[2], gv[3]));
        }
        asm volatile("s_waitcnt vmcnt(0)" ::: "memory");
        // SYNC1
        BARRIER();
        if (t == 0) {
            unsigned int T = (unsigned)(2 * step + 1);
            st_u32(fl_me, T);
            for (;;) {
                unsigned int f0 = ld_u32(fl_p0), f1 = ld_u32(fl_p1), f2 = ld_u32(fl_p2);
                if (f0 >= T && f1 >= T && f2 >= T) break;
                __builtin_amdgcn_s_sleep(1);
            }
        }
        BARRIER();
        // ---- combine gates -> c, h (t<128, unit pair 2t/2t+1, 4 batches) ----
        if (t < 128) {
            #pragma unroll
            for (int bp = 0; bp < 2; ++bp) {   // batch pairs (0,1) and (2,3)
                unsigned int Xi_a = ld_u32(&xgate[(gr * 4 + 0) * 512 + bp * 256 + 2 * t]);
                unsigned int Xi_b = ld_u32(&xgate[(gr * 4 + 0) * 512 + bp * 256 + 2 * t + 1]);
                unsigned int Xf_a = ld_u32(&xgate[(gr * 4 + 1) * 512 + bp * 256 + 2 * t]);
                unsigned int Xf_b = ld_u32(&xgate[(gr * 4 + 1) * 512 + bp * 256 + 2 * t + 1]);
                unsigned int Xg_a = ld_u32(&xgate[(gr * 4 + 2) * 512 + bp * 256 + 2 * t]);
                unsigned int Xg_b = ld_u32(&xgate[(gr * 4 + 2) * 512 + bp * 256 + 2 * t + 1]);
                unsigned int Xo_a = ld_u32(&xgate[(gr * 4 + 3) * 512 + bp * 256 + 2 * t]);
                unsigned int Xo_b = ld_u32(&xgate[(gr * 4 + 3) * 512 + bp * 256 + 2 * t + 1]);
                int b0i = bp * 2, b1i = bp * 2 + 1;
                cA[b0i] = h2f_lo(Xf_a) * cA[b0i] + h2f_lo(Xi_a) * h2f_lo(Xg_a);
                cB[b0i] = h2f_lo(Xf_b) * cB[b0i] + h2f_lo(Xi_b) * h2f_lo(Xg_b);
                hh2[b0i][t] = pk16(h2f_lo(Xo_a) * tanh_(cA[b0i]), h2f_lo(Xo_b) * tanh_(cB[b0i]));
                cA[b1i] = h2f_hi(Xf_a) * cA[b1i] + h2f_hi(Xi_a) * h2f_hi(Xg_a);
                cB[b1i] = h2f_hi(Xf_b) * cB[b1i] + h2f_hi(Xi_b) * h2f_hi(Xg_b);
                hh2[b1i][t] = pk16(h2f_hi(Xo_a) * tanh_(cA[b1i]), h2f_hi(Xo_b) * tanh_(cB[b1i]));
            }
        }
        BARRIER();
        // ---- C: q partials (W2 from L2, reused across 4 batches) ----
        {
            float q0 = 0.f, q1 = 0.f, q2 = 0.f, q3 = 0.f;
            #pragma unroll 4
            for (int i = 0; i < 16; ++i) {
                int k8 = kh * 16 + i;
                u32x4 wv = W28[k8 * 256 + r];
                u32x4 h0 = *(const u32x4*)&hh2[0][k8 * 4];
                u32x4 h1 = *(const u32x4*)&hh2[1][k8 * 4];
                u32x4 h2 = *(const u32x4*)&hh2[2][k8 * 4];
                u32x4 h3 = *(const u32x4*)&hh2[3][k8 * 4];
                q0 = dot4(wv, h0, q0); q1 = dot4(wv, h1, q1);
                q2 = dot4(wv, h2, q2); q3 = dot4(wv, h3, q3);
            }
            zsp[0][t] = q0; zsp[1][t] = q1; zsp[2][t] = q2; zsp[3][t] = q3;
        }
        BARRIER();
        if (t < 256) {
            #pragma unroll
            for (int b = 0; b < 4; ++b) {
                float q = (w2b_r + zsp[b][t] + zsp[b][t + 256]) * KEXP;
                float qn = __shfl_down(q, 1);
                if (!(t & 1)) qp2[b][t >> 1] = pk16(q, qn);
            }
        }
        BARRIER();
        // ---- D: u over my s-quarter, 4 batches; 4 threads per s ----
        float eb[4];
        {
            #pragma unroll
            for (int b = 0; b < 4; ++b) {
                const u32x4* pD = projT + (size_t)(bbase + b) * 16384 + pDoff;
                u32x4 pv[8];
                #pragma unroll
                for (int i = 0; i < 8; ++i) pv[i] = pD[i * 512];
                float u = 0.f;
                #pragma unroll
                for (int i = 0; i < 8; ++i) {
                    int c = qr * 8 + i;
                    u32x4 qh = *(const u32x4*)&qp2[b][c * 4];
                    u32x4 mv = *(const u32x4*)&mv2u[c * 4];
                    u = fdot2(mv[0], rcp1p2exp(hadd2u(pv[i][0], qh[0])), u);
                    u = fdot2(mv[1], rcp1p2exp(hadd2u(pv[i][1], qh[1])), u);
                    u = fdot2(mv[2], rcp1p2exp(hadd2u(pv[i][2], qh[2])), u);
                    u = fdot2(mv[3], rcp1p2exp(hadd2u(pv[i][3], qh[3])), u);
                }
                u += __shfl_xor(u, 1);
                u += __shfl_xor(u, 2);
                float e = __expf(u + svt);       // unnormalized, f16-safe (|u+svt| <= ~9)
                eb[b] = e;
                float en = __shfl_down(e, 4);
                if (!(t & 7)) p2u[b][t >> 3] = pk16(e, en);
                float ws = e;                    // each s counted 4x
                #pragma unroll
                for (int off = 1; off < 64; off <<= 1) ws += __shfl_xor(ws, off);
                if (lane == 0) wreds[w][b] = ws;
            }
        }
        BARRIER();
        // ---- F: din partials over my s-quarter (coalesced encT), 4 batches ----
        {
            #pragma unroll
            for (int b = 0; b < 4; ++b) {
                const u32x4* fD = encT + (size_t)(bbase + b) * 16384 + fDoff;
                u32x4 fv[8];
                #pragma unroll
                for (int j = 0; j < 8; ++j) fv[j] = fD[j * 256];
                float fa = 0.f;
                #pragma unroll
                for (int j = 0; j < 8; ++j) {
                    u32x4 pw = *(const u32x4*)&p2u[b][(scF * 8 + j) * 4];
                    fa = dot4(fv[j], pw, fa);
                }
                zsp[b][t] = fa;
            }
        }
        BARRIER();
        float dp[4] = {0.f, 0.f, 0.f, 0.f};
        if (t < 256) {
            #pragma unroll
            for (int b = 0; b < 4; ++b) {
                dp[b] = zsp[b][t] + zsp[b][t + 256];
                st_u32(&xd_me[b * 256 + t], __builtin_bit_cast(unsigned int, dp[b]));
            }
        }
        if (t == 0) {
            #pragma unroll
            for (int b = 0; b < 4; ++b) {
                float s = 0.f;
                #pragma unroll
                for (int k = 0; k < 8; ++k) s += wreds[k][b];
                st_u32(&xsum[q4 * 32 + b], __builtin_bit_cast(unsigned int, s * 0.25f));
            }
        }
        asm volatile("s_waitcnt vmcnt(0)" ::: "memory");
        // SYNC2 (din partials + e-sums)
        BARRIER();
        if (t == 0) {
            unsigned int T = (unsigned)(2 * step + 2);
            st_u32(fl_me, T);
            for (;;) {
                unsigned int f0 = ld_u32(fl_p0), f1 = ld_u32(fl_p1), f2 = ld_u32(fl_p2);
                if (f0 >= T && f1 >= T && f2 >= T) break;
                __builtin_amdgcn_s_sleep(1);
            }
            #pragma unroll
            for (int b = 0; b < 4; ++b) {
                float gs = 0.f;
                #pragma unroll
                for (int gp = 0; gp < 4; ++gp) gs += ld_f32(&xsum[(gr * 4 + gp) * 32 + b]);
                rsS[b] = rcp_(gs);
            }
        }
        BARRIER();
        {
            if (t < 256) {
                #pragma unroll
                for (int b = 0; b < 4; ++b) {
                    float d = dp[b];
                    #pragma unroll
                    for (int dg = 1; dg < 4; ++dg) {
                        int gp = (g + dg) & 3;
                        d += ld_f32(&xdin[(gr * 4 + gp) * 1024 + b * 256 + t]);
                    }
                    float dv = d * rsS[b];
                    float dvn = __shfl_down(dv, 1);
                    if (!(t & 1)) din2[b][t >> 1] = pk16(dv, dvn);
                }
            }
            if (!(t & 3)) {
                #pragma unroll
                for (int b = 0; b < 4; ++b)
                    out[(size_t)(bbase + b) * 262144 + (size_t)step * 512 + g * 128 + sl] = eb[b] * rsS[b];
            }
        }
        BARRIER();
    }
}

extern "C" void kernel_launch(void* const* d_in, const int* in_sizes, int n_in,
                              void* d_out, int out_size, void* d_ws, size_t ws_size,
                              hipStream_t stream) {
    const float* x      = (const float*)d_in[0];
    const float* encWih = (const float*)d_in[1];
    const float* encWhh = (const float*)d_in[2];
    const float* enc_b  = (const float*)d_in[3];
    const float* decWih = (const float*)d_in[4];
    const float* decWhh = (const float*)d_in[5];
    const float* dec_bp = (const float*)d_in[6];
    const float* W1w    = (const float*)d_in[7];
    const float* W1b    = (const float*)d_in[8];
    const float* W2w    = (const float*)d_in[9];
    const float* W2bp   = (const float*)d_in[10];
    const float* vtw    = (const float*)d_in[11];

    char* ws = (char*)d_ws;
    u32x4* We8 = (u32x4*)(ws);
    u32x4* Wi8 = (u32x4*)(ws + 524288);
    u32x4* Wh8 = (u32x4*)(ws + 1048576);
    u32x4* W28 = (u32x4*)(ws + 1572864);
    unsigned short* enc_h = (unsigned short*)(ws + 1703936);
    unsigned int*   encT  = (unsigned int*)(ws + 35258368);   // [b][64][256] u32x4 granules
    unsigned short* projT = (unsigned short*)(ws + 68812800); // [b][32][512] u32x4 granules
    float* hfin = (float*)(ws + 102367232);
    float* cfin = (float*)(ws + 102498304);

    // exchange area carved from enc_h region (dead after gemm<1,1> reads it)
    unsigned int* flags = (unsigned int*)(ws + 1703936);                  // 128 slots, 128B stride
    unsigned int* xsum  = (unsigned int*)(ws + 1703936 + 32768);          // 128 slots x 4, 128B stride
    unsigned int* xgate = (unsigned int*)(ws + 1703936 + 65536);          // [128][512] u32
    unsigned int* xdin  = (unsigned int*)(ws + 1703936 + 65536 + 262144); // [128][1024] u32

    unsigned short* Xproj = (unsigned short*)d_out;  // f16, consumed before decoder overwrites

    prep_kernel<<<416, 256, 0, stream>>>(encWhh, decWih, decWhh, W2w, We8, Wi8, Wh8, W28);
    gemm_kernel<0, 0><<<dim3(8, 1024), 256, 0, stream>>>(x, encWih, enc_b, Xproj, 1024, 1.0f);
    encoder_kernel<<<128, 1024, 0, stream>>>(Xproj, We8, hfin, cfin, enc_h, (unsigned int*)encT);
    gemm_kernel<1, 1><<<dim3(2, 1024), 256, 0, stream>>>(enc_h, W1w, W1b, projT, 256, KEXP);
    init_flags_kernel<<<1, 128, 0, stream>>>(flags);
    decoder_kernel<<<128, 512, 0, stream>>>(Wi8, Wh8, W28, dec_bp, W2bp, vtw,
                                            hfin, cfin, (const u32x4*)projT, (const u32x4*)encT,
                                            xgate, xdin, xsum, flags, (float*)d_out);
}

// Round 9
// 16126.965 us; speedup vs baseline: 1.5616x; 1.5616x over previous
//
#include <hip/hip_runtime.h>
#include <hip/hip_fp16.h>

typedef _Float16 h2_t __attribute__((ext_vector_type(2)));
typedef unsigned int u32x4 __attribute__((ext_vector_type(4)));

#define KEXP 2.8853900817779268f  // 2/ln2

// raw barrier: drain LDS only; global loads stay in flight
#define BARRIER() do { \
    asm volatile("s_waitcnt lgkmcnt(0)" ::: "memory"); \
    __builtin_amdgcn_s_barrier(); \
    asm volatile("" ::: "memory"); \
} while (0)

__device__ __forceinline__ float fdot2(unsigned int a, unsigned int b, float c) {
#if __has_builtin(__builtin_amdgcn_fdot2)
    return __builtin_amdgcn_fdot2(__builtin_bit_cast(h2_t, a), __builtin_bit_cast(h2_t, b), c, false);
#else
    h2_t ha = __builtin_bit_cast(h2_t, a), hb = __builtin_bit_cast(h2_t, b);
    return c + (float)ha[0]*(float)hb[0] + (float)ha[1]*(float)hb[1];
#endif
}

__device__ __forceinline__ float dot4(u32x4 a, u32x4 b, float c) {
    c = fdot2(a[0], b[0], c); c = fdot2(a[1], b[1], c);
    c = fdot2(a[2], b[2], c); c = fdot2(a[3], b[3], c);
    return c;
}

__device__ __forceinline__ unsigned int pk16(float a, float b) {
    auto h = __builtin_amdgcn_cvt_pkrtz(a, b);
    return __builtin_bit_cast(unsigned int, h);
}

__device__ __forceinline__ float rcp_(float x) {
#if __has_builtin(__builtin_amdgcn_rcpf)
    return __builtin_amdgcn_rcpf(x);
#else
    return 1.0f / x;
#endif
}

__device__ __forceinline__ float sigm(float x) { return rcp_(1.0f + __expf(-x)); }
__device__ __forceinline__ float tanh_(float x) {
    float e = __expf(2.0f * x);
    return 1.0f - 2.0f * rcp_(e + 1.0f);
}

__device__ __forceinline__ unsigned int rcp1p2exp(unsigned int s) {
    __half2 e = h2exp2(__builtin_bit_cast(__half2, s));
    __half2 d = __hadd2(e, __float2half2_rn(1.0f));
    return __builtin_bit_cast(unsigned int, h2rcp(d));
}
__device__ __forceinline__ unsigned int hadd2u(unsigned int a, unsigned int b) {
    return __builtin_bit_cast(unsigned int,
        __hadd2(__builtin_bit_cast(__half2, a), __builtin_bit_cast(__half2, b)));
}

__device__ __forceinline__ void st_u32(unsigned int* p, unsigned int v) {
    __hip_atomic_store(p, v, __ATOMIC_RELAXED, __HIP_MEMORY_SCOPE_AGENT);
}
__device__ __forceinline__ unsigned int ld_u32(const unsigned int* p) {
    return __hip_atomic_load(p, __ATOMIC_RELAXED, __HIP_MEMORY_SCOPE_AGENT);
}
__device__ __forceinline__ float ld_f32(const unsigned int* p) {
    return __builtin_bit_cast(float, ld_u32(p));
}
__device__ __forceinline__ float h2f_lo(unsigned int v) {
    return __half2float(__ushort_as_half((unsigned short)(v & 0xffffu)));
}
__device__ __forceinline__ float h2f_hi(unsigned int v) {
    return __half2float(__ushort_as_half((unsigned short)(v >> 16)));
}

__global__ void init_flags_kernel(unsigned int* flags) {
    flags[threadIdx.x * 32] = 0u;
}

// ---- prep: pack weights to f16, layout [k8][j]: u32x4 = 8 halves of row j, cols 8k8..8k8+7 ----
__global__ __launch_bounds__(256) void prep_kernel(
    const float* __restrict__ encWhh, const float* __restrict__ decWih,
    const float* __restrict__ decWhh, const float* __restrict__ W2w,
    u32x4* __restrict__ We8, u32x4* __restrict__ Wi8, u32x4* __restrict__ Wh8, u32x4* __restrict__ W28)
{
    int id = blockIdx.x * 256 + threadIdx.x;
    if (id < 3 * 32768) {
        int mat = id >> 15, local = id & 32767;
        int j = local & 1023, k8 = local >> 10;
        const float* src = mat == 0 ? encWhh : (mat == 1 ? decWih : decWhh);
        u32x4* dst = mat == 0 ? We8 : (mat == 1 ? Wi8 : Wh8);
        const float* p = src + (size_t)j * 256 + k8 * 8;
        float4 a = *(const float4*)p; float4 c = *(const float4*)(p + 4);
        u32x4 v; v[0] = pk16(a.x, a.y); v[1] = pk16(a.z, a.w);
        v[2] = pk16(c.x, c.y); v[3] = pk16(c.z, c.w);
        dst[k8 * 1024 + j] = v;
    } else {
        int local = id - 3 * 32768;
        if (local < 8192) {
            int m = local & 255, k8 = local >> 8;
            const float* p = W2w + (size_t)m * 256 + k8 * 8;
            float4 a = *(const float4*)p; float4 c = *(const float4*)(p + 4);
            u32x4 v; v[0] = pk16(a.x, a.y); v[1] = pk16(a.z, a.w);
            v[2] = pk16(c.x, c.y); v[3] = pk16(c.z, c.w);
            W28[k8 * 256 + m] = v;
        }
    }
}

// ---- GEMM: C(f16) = (A[M][256] * Bw[N][256]^T + bias) * scale
// TR_OUT=0: C[M][N] row-major.  TR_OUT=1 (proj): C = projT[b][c8(32)][s(512)] 16B granules.
template<int A_IS_F16, int TR_OUT>
__global__ __launch_bounds__(256) void gemm_kernel(
    const void* __restrict__ A_, const float* __restrict__ Bw,
    const float* __restrict__ bias, unsigned short* __restrict__ C, int N, float scale)
{
    __shared__ float As[16][68];
    __shared__ float Bs[16][132];
    const int t = threadIdx.x;
    const int row0 = blockIdx.y * 64, col0 = blockIdx.x * 128;
    const int ty = t >> 4, tx = t & 15;
    const int lm = t & 63, lkq = t >> 6;
    const int ln = t & 127, lkq2 = t >> 7;
    float acc[4][8] = {};
    for (int k0 = 0; k0 < 256; k0 += 16) {
        float4 av;
        if constexpr (A_IS_F16) {
            const unsigned short* A = (const unsigned short*)A_;
            uint2 ha = *(const uint2*)(A + (size_t)(row0 + lm) * 256 + k0 + lkq * 4);
            h2_t h0 = __builtin_bit_cast(h2_t, ha.x);
            h2_t h1 = __builtin_bit_cast(h2_t, ha.y);
            av = make_float4((float)h0[0], (float)h0[1], (float)h1[0], (float)h1[1]);
        } else {
            av = *(const float4*)((const float*)A_ + (size_t)(row0 + lm) * 256 + k0 + lkq * 4);
        }
        const float* bp = Bw + (size_t)(col0 + ln) * 256 + k0 + lkq2 * 8;
        float4 bv0 = *(const float4*)bp;
        float4 bv1 = *(const float4*)(bp + 4);
        __syncthreads();
        As[lkq * 4 + 0][lm] = av.x;
        As[lkq * 4 + 1][lm] = av.y;
        As[lkq * 4 + 2][lm] = av.z;
        As[lkq * 4 + 3][lm] = av.w;
        Bs[lkq2 * 8 + 0][ln] = bv0.x;
        Bs[lkq2 * 8 + 1][ln] = bv0.y;
        Bs[lkq2 * 8 + 2][ln] = bv0.z;
        Bs[lkq2 * 8 + 3][ln] = bv0.w;
        Bs[lkq2 * 8 + 4][ln] = bv1.x;
        Bs[lkq2 * 8 + 5][ln] = bv1.y;
        Bs[lkq2 * 8 + 6][ln] = bv1.z;
        Bs[lkq2 * 8 + 7][ln] = bv1.w;
        __syncthreads();
        #pragma unroll
        for (int kk = 0; kk < 16; ++kk) {
            float4 a = *(float4*)&As[kk][ty * 4];
            float4 b0 = *(float4*)&Bs[kk][tx * 8];
            float4 b1 = *(float4*)&Bs[kk][tx * 8 + 4];
            float ar[4] = {a.x, a.y, a.z, a.w};
            float br[8] = {b0.x, b0.y, b0.z, b0.w, b1.x, b1.y, b1.z, b1.w};
            #pragma unroll
            for (int i = 0; i < 4; ++i)
                #pragma unroll
                for (int j = 0; j < 8; ++j)
                    acc[i][j] = fmaf(ar[i], br[j], acc[i][j]);
        }
    }
    float bv[8];
    #pragma unroll
    for (int j = 0; j < 8; ++j) bv[j] = bias[col0 + tx * 8 + j];
    #pragma unroll
    for (int i = 0; i < 4; ++i) {
        unsigned int w0 = pk16((acc[i][0] + bv[0]) * scale, (acc[i][1] + bv[1]) * scale);
        unsigned int w1 = pk16((acc[i][2] + bv[2]) * scale, (acc[i][3] + bv[3]) * scale);
        unsigned int w2 = pk16((acc[i][4] + bv[4]) * scale, (acc[i][5] + bv[5]) * scale);
        unsigned int w3 = pk16((acc[i][6] + bv[6]) * scale, (acc[i][7] + bv[7]) * scale);
        uint4 val = make_uint4(w0, w1, w2, w3);
        if constexpr (TR_OUT) {
            int rr = row0 + ty * 4 + i;
            int bb = rr >> 9, s = rr & 511;
            int c8 = (col0 >> 3) + tx;
            ((uint4*)C)[(size_t)bb * 16384 + (size_t)c8 * 512 + s] = val;
        } else {
            *(uint4*)(C + (size_t)(row0 + ty * 4 + i) * N + col0 + tx * 8) = val;
        }
    }
}

// ---- encoder: 1 block per batch; emits enc_h [b][s][h] f16 and encT [b][c(64)][h(256)] 16B granules ----
__global__ __launch_bounds__(1024) void encoder_kernel(
    const unsigned short* __restrict__ Xproj, const u32x4* __restrict__ We8,
    float* __restrict__ hfin, float* __restrict__ cfin,
    unsigned short* __restrict__ enc_h, unsigned int* __restrict__ encT)
{
    const int b = blockIdx.x, t = threadIdx.x;
    __shared__ __align__(16) float zs[1024];
    __shared__ __align__(16) unsigned int hh2[128];
    if (t < 128) hh2[t] = 0u;
    float c_reg = 0.f, hprev = 0.f, hcur = 0.f;
    __syncthreads();
    const unsigned short* xp = Xproj + (size_t)b * 512 * 1024 + t;
    for (int step = 0; step < 512; ++step) {
        float acc = __half2float(__ushort_as_half(__builtin_nontemporal_load(xp)));
        #pragma unroll 8
        for (int k8 = 0; k8 < 32; ++k8) {
            u32x4 wv = We8[k8 * 1024 + t];
            u32x4 hv = *(const u32x4*)&hh2[k8 * 4];
            acc = dot4(wv, hv, acc);
        }
        zs[t] = acc;
        __syncthreads();
        if (t < 256) {
            float ig = sigm(zs[t]), fg = sigm(zs[t + 256]);
            float gg = tanh_(zs[t + 512]), og = sigm(zs[t + 768]);
            c_reg = fg * c_reg + ig * gg;
            float h = og * tanh_(c_reg);
            float hnb = __shfl_down(h, 1);
            if (!(t & 1)) hh2[t >> 1] = pk16(h, hnb);
            __builtin_nontemporal_store(__half_as_ushort(__float2half_rn(h)),
                                        enc_h + (size_t)(b * 512 + step) * 256 + t);
            if (step & 1) {
                int s2 = step >> 1;
                encT[(size_t)b * 65536 + (size_t)((s2 >> 2) * 256 + t) * 4 + (s2 & 3)] = pk16(hprev, h);
            }
            hprev = h; hcur = h;
        }
        __syncthreads();
        xp += 1024;
    }
    if (t < 256) { hfin[b * 256 + t] = hcur; cfin[b * 256 + t] = c_reg; }
}

// ---- decoder: 2 blocks per batch (role r: z-rows r*512.., attention s-half r*256..),
//      2 syncs/step (gates; din-partials + e-sums, deferred normalization) ----
__global__ __launch_bounds__(1024) void decoder_kernel(
    const u32x4* __restrict__ Wi8, const u32x4* __restrict__ Wh8, const u32x4* __restrict__ W28,
    const float* __restrict__ dec_b, const float* __restrict__ W2b, const float* __restrict__ vtw,
    const float* __restrict__ hfin, const float* __restrict__ cfin,
    const u32x4* __restrict__ projT, const u32x4* __restrict__ encT,
    unsigned int* __restrict__ xgate, unsigned int* __restrict__ xdin,
    unsigned int* __restrict__ xsum, unsigned int* __restrict__ flags,
    float* __restrict__ out)
{
    const int blk = blockIdx.x;
    const int b = blk & 127, r = blk >> 7;
    const int t = threadIdx.x;
    const int lane = t & 63, w = t >> 6;

    __shared__ __align__(16) float zs[1024];
    __shared__ __align__(16) unsigned int hh2[128];
    __shared__ __align__(16) unsigned int din2[128];
    __shared__ __align__(16) unsigned int qp2[128];
    __shared__ __align__(16) unsigned int mv2u[128];
    __shared__ __align__(16) unsigned int p2u[128];   // my s-half, unnormalized e pairs
    __shared__ float wreds[16];
    __shared__ float svtS, rsS;

    const int pr_me = b * 2 + r, pr_pa = b * 2 + (1 - r);
    unsigned int* fl_me = flags + pr_me * 32;
    unsigned int* fl_pa = flags + pr_pa * 32;
    unsigned int* xg_me = xgate + pr_me * 256;
    unsigned int* xd_me = xdin + pr_me * 256;

    const float bja = (t < 256) ? dec_b[r * 512 + t] : 0.f;
    const float bjb = (t < 256) ? dec_b[r * 512 + 256 + t] : 0.f;
    const float w2b_r = (t < 256) ? W2b[t] : 0.f;
    float c_reg = (t < 256) ? cfin[b * 256 + t] : 0.f;
    if (t < 128) { din2[t] = 0u; mv2u[t] = pk16(-2.f * vtw[2 * t], -2.f * vtw[2 * t + 1]); }
    if (t < 256) zs[t] = vtw[t];
    __syncthreads();
    if (t < 64) {
        float v = zs[t] + zs[t + 64] + zs[t + 128] + zs[t + 192];
        #pragma unroll
        for (int off = 1; off < 64; off <<= 1) v += __shfl_xor(v, off);
        if (t == 0) svtS = v;
    }
    if (t < 256) {
        float h0 = hfin[b * 256 + t];
        float hnb = __shfl_down(h0, 1);
        if (!(t & 1)) hh2[t >> 1] = pk16(h0, hnb);
    }
    __syncthreads();
    const float svt = svtS;

    // A mapping: thread (jl, kh): kh=0 -> Wih row (r*512+jl) . din ; kh=1 -> Whh row . h
    const int jl = t & 511, kh = t >> 9;
    const u32x4* wp = (kh ? Wh8 : Wi8) + (r * 512 + jl);
    const unsigned int* vls = kh ? (const unsigned int*)hh2 : (const unsigned int*)din2;
    // C mapping: row hC, k8-slice slC
    const int hC = t & 255, slC = t >> 8;
    // D mapping: 4 threads per s; my s-half = [r*256, r*256+256)
    const int sq = t >> 2, qr = t & 3;
    const u32x4* pD = projT + (size_t)b * 16384 + (size_t)(qr * 8) * 512 + r * 256 + sq;
    // F mapping: h = hC, 8 chunks of my 32-chunk half per slice
    const u32x4* fD = encT + (size_t)b * 16384 + (size_t)(r * 32 + slC * 8) * 256 + hC;
    float* outp = out + (size_t)b * 262144;

    for (int step = 0; step < 512; ++step) {
        // ---- A: z-half partials ----
        float acc = 0.f;
        #pragma unroll 8
        for (int k8 = 0; k8 < 32; ++k8) {
            u32x4 wv = wp[k8 * 1024];
            u32x4 hv = *(const u32x4*)&vls[k8 * 4];
            acc = dot4(wv, hv, acc);
        }
        zs[t] = acc;
        BARRIER();
        // ---- B: my two gates -> exchange ----
        unsigned int myg = 0u;
        if (t < 256) {
            float z_a = bja + zs[t] + zs[t + 512];
            float z_b = bjb + zs[t + 256] + zs[t + 768];
            float ga, gb;
            if (r == 0) { ga = sigm(z_a); gb = sigm(z_b); }      // i, f
            else        { ga = tanh_(z_a); gb = sigm(z_b); }     // g, o
            myg = (unsigned int)__half_as_ushort(__float2half_rn(ga)) |
                  ((unsigned int)__half_as_ushort(__float2half_rn(gb)) << 16);
            st_u32(&xg_me[t], myg);
            asm volatile("s_waitcnt vmcnt(0)" ::: "memory");
        }
        // SYNC1
        BARRIER();
        if (t == 0) {
            unsigned int T = (unsigned)(2 * step + 1);
            st_u32(fl_me, T);
            while (ld_u32(fl_pa) < T) __builtin_amdgcn_s_sleep(1);
        }
        BARRIER();
        // prefetch proj for D (consumed after 2 barriers; independent of q)
        u32x4 pv[8];
        #pragma unroll
        for (int i = 0; i < 8; ++i) pv[i] = pD[i * 512];
        // ---- combine gates -> c, h ----
        if (t < 256) {
            unsigned int og = ld_u32(&xgate[pr_pa * 256 + t]);
            float la = h2f_lo(myg), lb = h2f_hi(myg);
            float oa = h2f_lo(og),  ob = h2f_hi(og);
            float gi, gf, gg, go_;
            if (r == 0) { gi = la; gf = lb; gg = oa; go_ = ob; }
            else        { gg = la; go_ = lb; gi = oa; gf = ob; }
            c_reg = gf * c_reg + gi * gg;
            float h = go_ * tanh_(c_reg);
            float hnb = __shfl_down(h, 1);
            if (!(t & 1)) hh2[t >> 1] = pk16(h, hnb);
        }
        BARRIER();
        // ---- C: q partials (redundant in both blocks; 4 k-slices) ----
        {
            float qa = 0.f;
            #pragma unroll
            for (int i = 0; i < 8; ++i) {
                int k8 = slC * 8 + i;
                u32x4 wv = W28[k8 * 256 + hC];
                u32x4 hv = *(const u32x4*)&hh2[k8 * 4];
                qa = dot4(wv, hv, qa);
            }
            zs[t] = qa;
        }
        BARRIER();
        if (t < 256) {
            float q = (w2b_r + zs[t] + zs[t + 256] + zs[t + 512] + zs[t + 768]) * KEXP;
            float qnx = __shfl_down(q, 1);
            if (!(t & 1)) qp2[t >> 1] = pk16(q, qnx);
        }
        BARRIER();
        // ---- D: u over my s-half; 4 threads per s, 8 m-chunks each ----
        float e;
        u32x4 fv[8];
        {
            float u = 0.f;
            #pragma unroll
            for (int i = 0; i < 8; ++i) {
                int c = qr * 8 + i;
                u32x4 qh = *(const u32x4*)&qp2[c * 4];
                u32x4 mv = *(const u32x4*)&mv2u[c * 4];
                u = fdot2(mv[0], rcp1p2exp(hadd2u(pv[i][0], qh[0])), u);
                u = fdot2(mv[1], rcp1p2exp(hadd2u(pv[i][1], qh[1])), u);
                u = fdot2(mv[2], rcp1p2exp(hadd2u(pv[i][2], qh[2])), u);
                u = fdot2(mv[3], rcp1p2exp(hadd2u(pv[i][3], qh[3])), u);
            }
            u += __shfl_xor(u, 1);
            u += __shfl_xor(u, 2);
            e = __expf(u + svt);             // unnormalized; |u+svt| <= ~9 -> f16/f32 safe
            // prefetch encT for F
            #pragma unroll
            for (int j = 0; j < 8; ++j) fv[j] = fD[j * 256];
            float enx = __shfl_down(e, 4);
            if (!(t & 7)) p2u[t >> 3] = pk16(e, enx);
            float ws = e;                    // each s counted 4x
            #pragma unroll
            for (int off = 1; off < 64; off <<= 1) ws += __shfl_xor(ws, off);
            if (lane == 0) wreds[w] = ws;
        }
        BARRIER();
        // ---- F: din partial over my s-half (coalesced, prefetched) ----
        {
            float fa = 0.f;
            #pragma unroll
            for (int j = 0; j < 8; ++j) {
                u32x4 pw = *(const u32x4*)&p2u[(slC * 8 + j) * 4];
                fa = dot4(fv[j], pw, fa);
            }
            zs[t] = fa;
        }
        BARRIER();
        float dpart = 0.f;
        if (t < 256) {
            dpart = zs[t] + zs[t + 256] + zs[t + 512] + zs[t + 768];
            st_u32(&xd_me[t], __builtin_bit_cast(unsigned int, dpart));
        }
        if (t == 0) {
            float ls = 0.f;
            #pragma unroll
            for (int k = 0; k < 16; ++k) ls += wreds[k];
            st_u32(&xsum[pr_me * 32], __builtin_bit_cast(unsigned int, ls * 0.25f));
        }
        asm volatile("s_waitcnt vmcnt(0)" ::: "memory");
        // SYNC2 (din partials + e-sums)
        BARRIER();
        if (t == 0) {
            unsigned int T = (unsigned)(2 * step + 2);
            st_u32(fl_me, T);
            while (ld_u32(fl_pa) < T) __builtin_amdgcn_s_sleep(1);
            float ls = 0.f;
            #pragma unroll
            for (int k = 0; k < 16; ++k) ls += wreds[k];
            float gs = ls * 0.25f + ld_f32(&xsum[pr_pa * 32]);
            rsS = rcp_(gs);
        }
        BARRIER();
        {
            float rs = rsS;
            if (t < 256) {
                float dval = (dpart + ld_f32(&xdin[pr_pa * 256 + t])) * rs;
                float dnx = __shfl_down(dval, 1);
                if (!(t & 1)) din2[t >> 1] = pk16(dval, dnx);
            }
            if (!(t & 3))
                outp[(size_t)step * 512 + r * 256 + sq] = e * rs;
        }
        BARRIER();
    }
}

extern "C" void kernel_launch(void* const* d_in, const int* in_sizes, int n_in,
                              void* d_out, int out_size, void* d_ws, size_t ws_size,
                              hipStream_t stream) {
    const float* x      = (const float*)d_in[0];
    const float* encWih = (const float*)d_in[1];
    const float* encWhh = (const float*)d_in[2];
    const float* enc_b  = (const float*)d_in[3];
    const float* decWih = (const float*)d_in[4];
    const float* decWhh = (const float*)d_in[5];
    const float* dec_bp = (const float*)d_in[6];
    const float* W1w    = (const float*)d_in[7];
    const float* W1b    = (const float*)d_in[8];
    const float* W2w    = (const float*)d_in[9];
    const float* W2bp   = (const float*)d_in[10];
    const float* vtw    = (const float*)d_in[11];

    char* ws = (char*)d_ws;
    u32x4* We8 = (u32x4*)(ws);
    u32x4* Wi8 = (u32x4*)(ws + 524288);
    u32x4* Wh8 = (u32x4*)(ws + 1048576);
    u32x4* W28 = (u32x4*)(ws + 1572864);
    unsigned short* enc_h = (unsigned short*)(ws + 1703936);
    unsigned int*   encT  = (unsigned int*)(ws + 35258368);   // [b][64][256] u32x4 granules
    unsigned short* projT = (unsigned short*)(ws + 68812800); // [b][32][512] u32x4 granules
    float* hfin = (float*)(ws + 102367232);
    float* cfin = (float*)(ws + 102498304);

    // exchange area carved from enc_h region (dead after gemm<1,1> reads it)
    unsigned int* flags = (unsigned int*)(ws + 1703936);                  // 256 slots, 128B stride
    unsigned int* xsum  = (unsigned int*)(ws + 1703936 + 32768);          // 256 slots, 128B stride
    unsigned int* xgate = (unsigned int*)(ws + 1703936 + 65536);          // [256][256] u32
    unsigned int* xdin  = (unsigned int*)(ws + 1703936 + 65536 + 262144); // [256][256] u32

    unsigned short* Xproj = (unsigned short*)d_out;  // f16, consumed before decoder overwrites

    prep_kernel<<<416, 256, 0, stream>>>(encWhh, decWih, decWhh, W2w, We8, Wi8, Wh8, W28);
    gemm_kernel<0, 0><<<dim3(8, 1024), 256, 0, stream>>>(x, encWih, enc_b, Xproj, 1024, 1.0f);
    encoder_kernel<<<128, 1024, 0, stream>>>(Xproj, We8, hfin, cfin, enc_h, (unsigned int*)encT);
    gemm_kernel<1, 1><<<dim3(2, 1024), 256, 0, stream>>>(enc_h, W1w, W1b, projT, 256, KEXP);
    init_flags_kernel<<<1, 256, 0, stream>>>(flags);
    decoder_kernel<<<256, 1024, 0, stream>>>(Wi8, Wh8, W28, dec_bp, W2bp, vtw,
                                             hfin, cfin, (const u32x4*)projT, (const u32x4*)encT,
                                             xgate, xdin, xsum, flags, (float*)d_out);
}